// Round 2
// baseline (8857.645 us; speedup 1.0000x reference)
//
#include <hip/hip_runtime.h>

#define N_NODES 100000
#define N_EDGES 200000
#define N_GRAPHS 4096
#define D 256
#define D2 512
#define OUTD 768
#define LAYERS 4
#define NODE_FEATS 9
#define EDGE_FEATS 3
#define NODE_VOCAB 119
#define EDGE_VOCAB 22
#define RB 32          // rows per block in fused MLP
#define PAD 36         // LDS row stride (floats): 144B, 16B-aligned for b128 reads

// ---------------- embedding encode (nodes only; edges fused into scatter) ----------------
__global__ __launch_bounds__(256) void encode_nodes_k(const int* __restrict__ xcat,
                                                      const float* __restrict__ tab,
                                                      float* __restrict__ X) {
    int n = blockIdx.x;
    int d = threadIdx.x;
    float acc = 0.f;
#pragma unroll
    for (int f = 0; f < NODE_FEATS; ++f) {
        int idx = xcat[n * NODE_FEATS + f];
        acc += tab[((size_t)f * NODE_VOCAB + idx) * D + d];
    }
    X[(size_t)n * D + d] = acc;
}

// ---------------- edge message scatter-add (edge embedding computed on the fly) ---------
// block = 256 threads = 4 edges x 64 lanes, float4 per lane
__global__ __launch_bounds__(256) void scatter_k(const float* __restrict__ X,
                                                 const float* __restrict__ eemb,
                                                 const int* __restrict__ eattr,
                                                 const int* __restrict__ eidx,
                                                 float* AGG) {
    int e = blockIdx.x * 4 + (threadIdx.x >> 6);
    int lane = threadIdx.x & 63;
    int src = eidx[e];
    int dst = eidx[N_EDGES + e];
    float4 ev = make_float4(0.f, 0.f, 0.f, 0.f);
#pragma unroll
    for (int f = 0; f < EDGE_FEATS; ++f) {
        int idx = eattr[e * EDGE_FEATS + f];
        const float4 t = *(const float4*)(eemb + ((size_t)f * EDGE_VOCAB + idx) * D + lane * 4);
        ev.x += t.x; ev.y += t.y; ev.z += t.z; ev.w += t.w;
    }
    const float4 xv = *(const float4*)(X + (size_t)src * D + lane * 4);
    float4 m;
    m.x = fmaxf(xv.x + ev.x, 0.f);
    m.y = fmaxf(xv.y + ev.y, 0.f);
    m.z = fmaxf(xv.z + ev.z, 0.f);
    m.w = fmaxf(xv.w + ev.w, 0.f);
    float* a = AGG + (size_t)dst * D + lane * 4;
    unsafeAtomicAdd(a + 0, m.x);
    unsafeAtomicAdd(a + 1, m.y);
    unsafeAtomicAdd(a + 2, m.z);
    unsafeAtomicAdd(a + 3, m.w);
}

// ---------------- fused per-layer MLP: x = relu(relu((x+agg)@W1+b1)@W2+b2) --------------
// block handles RB=32 rows; 256 threads. LDS ~110 KB -> 1 block/CU.
__global__ __launch_bounds__(256) void fused_mlp_k(const float* __restrict__ X,
                                                   const float* __restrict__ AGG,
                                                   const float* __restrict__ W1,
                                                   const float* __restrict__ b1,
                                                   const float* __restrict__ W2,
                                                   const float* __restrict__ b2,
                                                   float* Xout) {
    __shared__ float in_t[D][PAD];    //  36,864 B  (transposed input rows)
    __shared__ float mid_t[D2][PAD];  //  73,728 B  (transposed hidden)
    const int tid = threadIdx.x;
    const size_t r0 = (size_t)blockIdx.x * RB;

    // load + transpose input (x + agg)
#pragma unroll
    for (int i = 0; i < RB; ++i) {
        size_t off = (r0 + i) * D + tid;
        in_t[tid][i] = X[off] + AGG[off];
    }
    __syncthreads();

    // GEMM1 + relu -> mid_t   (thread -> cols tid, tid+256)
    float acc0[RB], acc1[RB];
    {
        float bias0 = b1[tid], bias1 = b1[tid + 256];
#pragma unroll
        for (int i = 0; i < RB; ++i) { acc0[i] = bias0; acc1[i] = bias1; }
        for (int k = 0; k < D; ++k) {
            float w0 = W1[(size_t)k * D2 + tid];
            float w1 = W1[(size_t)k * D2 + 256 + tid];
            const float4* a4 = (const float4*)in_t[k];
#pragma unroll
            for (int i = 0; i < RB / 4; ++i) {
                float4 a = a4[i];
                acc0[4*i+0] += a.x * w0;  acc1[4*i+0] += a.x * w1;
                acc0[4*i+1] += a.y * w0;  acc1[4*i+1] += a.y * w1;
                acc0[4*i+2] += a.z * w0;  acc1[4*i+2] += a.z * w1;
                acc0[4*i+3] += a.w * w0;  acc1[4*i+3] += a.w * w1;
            }
        }
    }
#pragma unroll
    for (int i = 0; i < RB; ++i) {
        mid_t[tid][i]       = fmaxf(acc0[i], 0.f);
        mid_t[tid + 256][i] = fmaxf(acc1[i], 0.f);
    }
    __syncthreads();

    // GEMM2 + relu -> Xout (in-place over X is safe: block only touches its own rows)
    float acc2[RB];
    {
        float bias2 = b2[tid];
#pragma unroll
        for (int i = 0; i < RB; ++i) acc2[i] = bias2;
        for (int k = 0; k < D2; ++k) {
            float w = W2[(size_t)k * D + tid];
            const float4* a4 = (const float4*)mid_t[k];
#pragma unroll
            for (int i = 0; i < RB / 4; ++i) {
                float4 a = a4[i];
                acc2[4*i+0] += a.x * w;
                acc2[4*i+1] += a.y * w;
                acc2[4*i+2] += a.z * w;
                acc2[4*i+3] += a.w * w;
            }
        }
    }
#pragma unroll
    for (int i = 0; i < RB; ++i)
        Xout[(r0 + i) * D + tid] = fmaxf(acc2[i], 0.f);
}

// ---------------- graph pooling ----------------
__global__ __launch_bounds__(256) void pool_k(const float* __restrict__ X,
                                              const int* __restrict__ batch,
                                              float* G) {
    int n = blockIdx.x * 4 + (threadIdx.x >> 6);
    int lane = threadIdx.x & 63;
    int g = batch[n];
    const float4 xv = *(const float4*)(X + (size_t)n * D + lane * 4);
    float* p = G + (size_t)g * D + lane * 4;
    unsafeAtomicAdd(p + 0, xv.x);
    unsafeAtomicAdd(p + 1, xv.y);
    unsafeAtomicAdd(p + 2, xv.z);
    unsafeAtomicAdd(p + 3, xv.w);
}

// ---------------- fused final MLP + row L2 normalize (one graph per block) --------------
__global__ __launch_bounds__(256) void final_k(const float* __restrict__ G,
                                               const float* __restrict__ pW1,
                                               const float* __restrict__ pb1,
                                               const float* __restrict__ pW2,
                                               const float* __restrict__ pb2,
                                               float* __restrict__ out) {
    __shared__ float gin[D];
    __shared__ float mid[D];
    __shared__ float red[256];
    int n = blockIdx.x, t = threadIdx.x;
    gin[t] = G[(size_t)n * D + t];
    __syncthreads();
    float acc = pb1[t];
    for (int k = 0; k < D; ++k) acc += gin[k] * pW1[(size_t)k * D + t];
    mid[t] = fmaxf(acc, 0.f);
    __syncthreads();
    float a0 = pb2[t], a1 = pb2[t + 256], a2 = pb2[t + 512];
    for (int k = 0; k < D; ++k) {
        float m = mid[k];
        a0 += m * pW2[(size_t)k * OUTD + t];
        a1 += m * pW2[(size_t)k * OUTD + 256 + t];
        a2 += m * pW2[(size_t)k * OUTD + 512 + t];
    }
    red[t] = a0 * a0 + a1 * a1 + a2 * a2;
    __syncthreads();
    for (int s = 128; s > 0; s >>= 1) {
        if (t < s) red[t] += red[t + s];
        __syncthreads();
    }
    float inv = 1.f / fmaxf(sqrtf(red[0]), 1e-12f);
    out[(size_t)n * OUTD + t]       = a0 * inv;
    out[(size_t)n * OUTD + 256 + t] = a1 * inv;
    out[(size_t)n * OUTD + 512 + t] = a2 * inv;
}

extern "C" void kernel_launch(void* const* d_in, const int* in_sizes, int n_in,
                              void* d_out, int out_size, void* d_ws, size_t ws_size,
                              hipStream_t stream) {
    const int*   x_cat      = (const int*)d_in[0];
    const int*   edge_attr  = (const int*)d_in[1];
    const int*   edge_index = (const int*)d_in[2];
    const int*   batch      = (const int*)d_in[3];
    const float* node_emb   = (const float*)d_in[4];
    const float* edge_emb   = (const float*)d_in[5];
    const float* W1 = (const float*)d_in[6];
    const float* b1 = (const float*)d_in[7];
    const float* W2 = (const float*)d_in[8];
    const float* b2 = (const float*)d_in[9];
    const float* pW1 = (const float*)d_in[10];
    const float* pb1 = (const float*)d_in[11];
    const float* pW2 = (const float*)d_in[12];
    const float* pb2 = (const float*)d_in[13];
    float* out = (float*)d_out;

    float* X   = (float*)d_ws;                 // 25.6M floats (102.4 MB)
    float* AGG = X + (size_t)N_NODES * D;      // 25.6M floats (102.4 MB)
    float* G   = AGG + (size_t)N_NODES * D;    // 1.05M floats (4.2 MB)
    // total ~209 MB of workspace

    encode_nodes_k<<<N_NODES, 256, 0, stream>>>(x_cat, node_emb, X);

    for (int l = 0; l < LAYERS; ++l) {
        hipMemsetAsync(AGG, 0, (size_t)N_NODES * D * sizeof(float), stream);
        scatter_k<<<N_EDGES / 4, 256, 0, stream>>>(X, edge_emb, edge_attr, edge_index, AGG);
        fused_mlp_k<<<N_NODES / RB, 256, 0, stream>>>(
            X, AGG,
            W1 + (size_t)l * D * D2, b1 + (size_t)l * D2,
            W2 + (size_t)l * D2 * D, b2 + (size_t)l * D,
            X);
    }

    hipMemsetAsync(G, 0, (size_t)N_GRAPHS * D * sizeof(float), stream);
    pool_k<<<N_NODES / 4, 256, 0, stream>>>(X, batch, G);
    final_k<<<N_GRAPHS, 256, 0, stream>>>(G, pW1, pb1, pW2, pb2, out);
}

// Round 3
// 1518.426 us; speedup vs baseline: 5.8334x; 5.8334x over previous
//
#include <hip/hip_runtime.h>

#define N_NODES 100000
#define N_EDGES 200000
#define N_GRAPHS 4096
#define D 256
#define D2 512
#define OUTD 768
#define LAYERS 4
#define NODE_FEATS 9
#define EDGE_FEATS 3
#define NODE_VOCAB 119
#define EDGE_VOCAB 22
#define BM 32            // rows per MLP block

typedef __attribute__((ext_vector_type(8))) short bf16x8;
typedef __attribute__((ext_vector_type(4))) float f32x4;
typedef unsigned short ushort_t;
typedef unsigned int uint_t;

__device__ __forceinline__ ushort_t f2b(float f) {   // f32 -> bf16 bits, RNE
    union { float f; uint_t u; } x; x.f = f;
    uint_t r = (x.u + 0x7FFFu + ((x.u >> 16) & 1u)) >> 16;
    return (ushort_t)r;
}

__device__ __forceinline__ int lower_bound_i(const int* a, int n, int v) {
    int lo = 0, hi = n;
    while (lo < hi) { int mid = (lo + hi) >> 1; if (a[mid] < v) lo = mid + 1; else hi = mid; }
    return lo;
}

// ---------------- embedding encode (nodes) ----------------
__global__ __launch_bounds__(256) void encode_nodes_k(const int* __restrict__ xcat,
                                                      const float* __restrict__ tab,
                                                      float* __restrict__ X) {
    int n = blockIdx.x, d = threadIdx.x;
    float acc = 0.f;
#pragma unroll
    for (int f = 0; f < NODE_FEATS; ++f) {
        int idx = xcat[n * NODE_FEATS + f];
        acc += tab[((size_t)f * NODE_VOCAB + idx) * D + d];
    }
    X[(size_t)n * D + d] = acc;
}

// ---------------- CSR build ----------------
__global__ __launch_bounds__(256) void count_k(const int* __restrict__ eidx, int* deg) {
    int e = blockIdx.x * 256 + threadIdx.x;
    if (e < N_EDGES) atomicAdd(&deg[eidx[N_EDGES + e]], 1);
}

#define SCAN_B 1024
__global__ __launch_bounds__(256) void scan1_k(const int* __restrict__ deg,
                                               int* __restrict__ excl, int* __restrict__ bsum) {
    __shared__ int sh[256];
    int b = blockIdx.x, t = threadIdx.x;
    int base = b * SCAN_B + t * 4;
    int d0 = (base + 0) < N_NODES ? deg[base + 0] : 0;
    int d1 = (base + 1) < N_NODES ? deg[base + 1] : 0;
    int d2 = (base + 2) < N_NODES ? deg[base + 2] : 0;
    int d3 = (base + 3) < N_NODES ? deg[base + 3] : 0;
    int s = d0 + d1 + d2 + d3;
    sh[t] = s; __syncthreads();
    for (int off = 1; off < 256; off <<= 1) {
        int x = (t >= off) ? sh[t - off] : 0;
        __syncthreads();
        sh[t] += x;
        __syncthreads();
    }
    int incl = sh[t];
    int ex = incl - s;
    if (base + 0 < N_NODES) excl[base + 0] = ex;
    if (base + 1 < N_NODES) excl[base + 1] = ex + d0;
    if (base + 2 < N_NODES) excl[base + 2] = ex + d0 + d1;
    if (base + 3 < N_NODES) excl[base + 3] = ex + d0 + d1 + d2;
    if (t == 255) bsum[b] = incl;
}

__global__ void scan2_k(int* bsum, int nb) {   // 1 block of 128 threads
    __shared__ int sh[128];
    int t = threadIdx.x;
    int v = (t < nb) ? bsum[t] : 0;
    sh[t] = v; __syncthreads();
    for (int off = 1; off < 128; off <<= 1) {
        int x = (t >= off) ? sh[t - off] : 0;
        __syncthreads();
        sh[t] += x;
        __syncthreads();
    }
    if (t < nb) bsum[t] = sh[t] - v;   // exclusive over blocks
}

__global__ __launch_bounds__(256) void scan3_k(int* __restrict__ offs, int* __restrict__ cursor,
                                               const int* __restrict__ bsum) {
    int i = blockIdx.x * 256 + threadIdx.x;
    if (i < N_NODES) {
        int v = offs[i] + bsum[i >> 10];
        offs[i] = v;
        cursor[i] = v;
    }
}

__global__ __launch_bounds__(256) void fill_k(const int* __restrict__ eidx,
                                              int* cursor, int* __restrict__ elist) {
    int e = blockIdx.x * 256 + threadIdx.x;
    if (e < N_EDGES) {
        int pos = atomicAdd(&cursor[eidx[N_EDGES + e]], 1);
        elist[pos] = e;
    }
}

// ---------------- gather aggregation: H = bf16(X[n] + sum relu(X[src]+e_emb)) ------------
__global__ __launch_bounds__(256) void gather_k(const float* __restrict__ X,
                                                const float* __restrict__ eemb,
                                                const int* __restrict__ eattr,
                                                const int* __restrict__ eidx,
                                                const int* __restrict__ offs,
                                                const int* __restrict__ deg,
                                                const int* __restrict__ elist,
                                                ushort_t* __restrict__ H) {
    int n = blockIdx.x, t = threadIdx.x;
    int start = offs[n], dg = deg[n];
    float acc = X[(size_t)n * D + t];
    for (int i = 0; i < dg; ++i) {
        int e = elist[start + i];
        int src = eidx[e];
        float ev = 0.f;
#pragma unroll
        for (int f = 0; f < EDGE_FEATS; ++f) {
            int idx = eattr[e * EDGE_FEATS + f];
            ev += eemb[((size_t)f * EDGE_VOCAB + idx) * D + t];
        }
        acc += fmaxf(X[(size_t)src * D + t] + ev, 0.f);
    }
    H[(size_t)n * D + t] = f2b(acc);
}

// ---------------- weight pre-pack into MFMA fragment layout (bf16) ----------------
// apack1[l][ntg(32)][kk(8)][lane(64)][j(8)] = W1[l][kk*32+(lane>>4)*8+j][ntg*16+(lane&15)]
__global__ __launch_bounds__(256) void pack1_k(const float* __restrict__ W1, ushort_t* __restrict__ apack) {
    size_t i = (size_t)blockIdx.x * 256 + threadIdx.x;   // 65536 groups
    int l = (int)(i >> 14);
    int rem = (int)(i & 16383);
    int ntg = rem >> 9;
    int rem2 = rem & 511;
    int kk = rem2 >> 6;
    int lane = rem2 & 63;
    int n = ntg * 16 + (lane & 15);
    int k0 = kk * 32 + (lane >> 4) * 8;
    const float* w = W1 + ((size_t)l * D + k0) * D2 + n;
    ushort_t* o = apack + i * 8;
#pragma unroll
    for (int j = 0; j < 8; ++j) o[j] = f2b(w[(size_t)j * D2]);
}

// bpack2[l][ntg(16)][kk(16)][lane(64)][j(8)] = W2[l][kk*32+(lane>>4)*8+j][ntg*16+(lane&15)]
__global__ __launch_bounds__(256) void pack2_k(const float* __restrict__ W2, ushort_t* __restrict__ bpack) {
    size_t i = (size_t)blockIdx.x * 256 + threadIdx.x;   // 65536 groups
    int l = (int)(i >> 14);
    int rem = (int)(i & 16383);
    int ntg = rem >> 10;
    int rem2 = rem & 1023;
    int kk = rem2 >> 6;
    int lane = rem2 & 63;
    int n = ntg * 16 + (lane & 15);
    int k0 = kk * 32 + (lane >> 4) * 8;
    const float* w = W2 + ((size_t)l * D2 + k0) * D + n;
    ushort_t* o = bpack + i * 8;
#pragma unroll
    for (int j = 0; j < 8; ++j) o[j] = f2b(w[(size_t)j * D]);
}

// ---------------- fused MFMA MLP: X = relu(relu(H@W1+b1)@W2+b2) ----------------
// 256 threads = 4 waves, BM=32 rows/block, 48KB LDS -> 3 blocks/CU.
__global__ __launch_bounds__(256) void mlp_k(const ushort_t* __restrict__ H,
                                             const ushort_t* __restrict__ apack,
                                             const float* __restrict__ b1,
                                             const ushort_t* __restrict__ bpack,
                                             const float* __restrict__ b2,
                                             float* __restrict__ X) {
    __shared__ __align__(16) ushort_t hA[BM * D];     // 16KB, row 512B, XOR-swizzled
    __shared__ __align__(16) ushort_t mid[BM * D2];   // 32KB, row 1024B, XOR-swizzled
    const int t = threadIdx.x;
    const int wid = t >> 6, lane = t & 63;
    const int l15 = lane & 15, g = lane >> 4;
    const size_t r0 = (size_t)blockIdx.x * BM;

    // ---- stage H tile (contiguous 16KB) with XOR swizzle ----
    {
        const char* src = (const char*)(H + r0 * D);
#pragma unroll
        for (int c = 0; c < 4; ++c) {
            int Lb = (c * 256 + t) * 16;
            int row = Lb >> 9;
            int Sb = Lb ^ ((row & 7) << 4);
            *(uint4*)((char*)hA + Sb) = *(const uint4*)(src + Lb);
        }
    }
    __syncthreads();

    // ---- GEMM1 (transposed orientation): mid[m][n] = relu(H@W1 + b1), wave owns 128 n-cols
    {
        f32x4 acc[8][2];
#pragma unroll
        for (int i = 0; i < 8; ++i) {
            f32x4 z = {0.f, 0.f, 0.f, 0.f};
            acc[i][0] = z; acc[i][1] = z;
        }
#pragma unroll
        for (int kk = 0; kk < 8; ++kk) {
            bf16x8 Bf[2];
#pragma unroll
            for (int mt = 0; mt < 2; ++mt) {
                int m = mt * 16 + l15;
                int byte_ = (m * 512 + (kk * 32 + g * 8) * 2) ^ ((m & 7) << 4);
                Bf[mt] = *(const bf16x8*)((const char*)hA + byte_);
            }
#pragma unroll
            for (int nt = 0; nt < 8; ++nt) {
                int ntg = wid * 8 + nt;
                bf16x8 Af = *(const bf16x8*)(apack + ((size_t)(ntg * 8 + kk) * 64 + lane) * 8);
                acc[nt][0] = __builtin_amdgcn_mfma_f32_16x16x32_bf16(Af, Bf[0], acc[nt][0], 0, 0, 0);
                acc[nt][1] = __builtin_amdgcn_mfma_f32_16x16x32_bf16(Af, Bf[1], acc[nt][1], 0, 0, 0);
            }
        }
        // bias + relu + pack to mid LDS (lane holds 4 consecutive n at fixed m)
#pragma unroll
        for (int nt = 0; nt < 8; ++nt) {
            int ntg = wid * 8 + nt;
            int n0 = ntg * 16 + g * 4;
            f32x4 bv = *(const f32x4*)(b1 + n0);
#pragma unroll
            for (int mt = 0; mt < 2; ++mt) {
                int m = mt * 16 + l15;
                ushort_t us[4];
#pragma unroll
                for (int r = 0; r < 4; ++r)
                    us[r] = f2b(fmaxf(acc[nt][mt][r] + bv[r], 0.f));
                uint2 pk;
                pk.x = (uint_t)us[0] | ((uint_t)us[1] << 16);
                pk.y = (uint_t)us[2] | ((uint_t)us[3] << 16);
                int byte_ = (m * 1024 + n0 * 2) ^ ((m & 7) << 4);
                *(uint2*)((char*)mid + byte_) = pk;
            }
        }
    }
    __syncthreads();

    // ---- GEMM2 (standard): X = relu(mid@W2 + b2), wave owns 64 n-cols
    {
        f32x4 acc[4][2];
#pragma unroll
        for (int i = 0; i < 4; ++i) {
            f32x4 z = {0.f, 0.f, 0.f, 0.f};
            acc[i][0] = z; acc[i][1] = z;
        }
#pragma unroll
        for (int kk = 0; kk < 16; ++kk) {
            bf16x8 Af[2];
#pragma unroll
            for (int mt = 0; mt < 2; ++mt) {
                int m = mt * 16 + l15;
                int byte_ = (m * 1024 + (kk * 32 + g * 8) * 2) ^ ((m & 7) << 4);
                Af[mt] = *(const bf16x8*)((const char*)mid + byte_);
            }
#pragma unroll
            for (int nt = 0; nt < 4; ++nt) {
                int ntg = wid * 4 + nt;
                bf16x8 Bf = *(const bf16x8*)(bpack + ((size_t)(ntg * 16 + kk) * 64 + lane) * 8);
                acc[nt][0] = __builtin_amdgcn_mfma_f32_16x16x32_bf16(Af[0], Bf, acc[nt][0], 0, 0, 0);
                acc[nt][1] = __builtin_amdgcn_mfma_f32_16x16x32_bf16(Af[1], Bf, acc[nt][1], 0, 0, 0);
            }
        }
        // bias + relu + store f32 (D: col n = lane&15, row m = (lane>>4)*4+r)
#pragma unroll
        for (int nt = 0; nt < 4; ++nt) {
            int ntg = wid * 4 + nt;
            int n = ntg * 16 + l15;
            float bb = b2[n];
#pragma unroll
            for (int mt = 0; mt < 2; ++mt) {
#pragma unroll
                for (int r = 0; r < 4; ++r) {
                    int m = mt * 16 + g * 4 + r;
                    X[(r0 + m) * D + n] = fmaxf(acc[nt][mt][r] + bb, 0.f);
                }
            }
        }
    }
}

// ---------------- pooling via sorted batch (segment sums, no atomics) ----------------
__global__ __launch_bounds__(256) void pool_k(const float* __restrict__ X,
                                              const int* __restrict__ batch,
                                              float* __restrict__ G) {
    int gph = blockIdx.x, t = threadIdx.x;
    int lo = lower_bound_i(batch, N_NODES, gph);
    int hi = lower_bound_i(batch, N_NODES, gph + 1);
    float acc = 0.f;
    for (int n = lo; n < hi; ++n) acc += X[(size_t)n * D + t];
    G[(size_t)gph * D + t] = acc;
}

// ---------------- fused final MLP + row L2 normalize ----------------
__global__ __launch_bounds__(256) void final_k(const float* __restrict__ G,
                                               const float* __restrict__ pW1,
                                               const float* __restrict__ pb1,
                                               const float* __restrict__ pW2,
                                               const float* __restrict__ pb2,
                                               float* __restrict__ out) {
    __shared__ float gin[D];
    __shared__ float mid[D];
    __shared__ float red[256];
    int n = blockIdx.x, t = threadIdx.x;
    gin[t] = G[(size_t)n * D + t];
    __syncthreads();
    float acc = pb1[t];
    for (int k = 0; k < D; ++k) acc += gin[k] * pW1[(size_t)k * D + t];
    mid[t] = fmaxf(acc, 0.f);
    __syncthreads();
    float a0 = pb2[t], a1 = pb2[t + 256], a2 = pb2[t + 512];
    for (int k = 0; k < D; ++k) {
        float m = mid[k];
        a0 += m * pW2[(size_t)k * OUTD + t];
        a1 += m * pW2[(size_t)k * OUTD + 256 + t];
        a2 += m * pW2[(size_t)k * OUTD + 512 + t];
    }
    red[t] = a0 * a0 + a1 * a1 + a2 * a2;
    __syncthreads();
    for (int s = 128; s > 0; s >>= 1) {
        if (t < s) red[t] += red[t + s];
        __syncthreads();
    }
    float inv = 1.f / fmaxf(sqrtf(red[0]), 1e-12f);
    out[(size_t)n * OUTD + t]       = a0 * inv;
    out[(size_t)n * OUTD + 256 + t] = a1 * inv;
    out[(size_t)n * OUTD + 512 + t] = a2 * inv;
}

extern "C" void kernel_launch(void* const* d_in, const int* in_sizes, int n_in,
                              void* d_out, int out_size, void* d_ws, size_t ws_size,
                              hipStream_t stream) {
    const int*   x_cat      = (const int*)d_in[0];
    const int*   edge_attr  = (const int*)d_in[1];
    const int*   edge_index = (const int*)d_in[2];
    const int*   batch      = (const int*)d_in[3];
    const float* node_emb   = (const float*)d_in[4];
    const float* edge_emb   = (const float*)d_in[5];
    const float* W1  = (const float*)d_in[6];
    const float* b1  = (const float*)d_in[7];
    const float* W2  = (const float*)d_in[8];
    const float* b2  = (const float*)d_in[9];
    const float* pW1 = (const float*)d_in[10];
    const float* pb1 = (const float*)d_in[11];
    const float* pW2 = (const float*)d_in[12];
    const float* pb2 = (const float*)d_in[13];
    float* out = (float*)d_out;

    // ---- workspace carve (~162 MB) ----
    char* p = (char*)d_ws;
    auto carve = [&](size_t bytes) { char* q = p; p += (bytes + 255) & ~(size_t)255; return q; };
    float*    X      = (float*)carve((size_t)N_NODES * D * 4);       // 102.4 MB
    ushort_t* H      = (ushort_t*)carve((size_t)N_NODES * D * 2);    //  51.2 MB
    float*    G      = (float*)carve((size_t)N_GRAPHS * D * 4);      //   4.2 MB
    int*      deg    = (int*)carve((size_t)N_NODES * 4);
    int*      offs   = (int*)carve((size_t)(N_NODES + 8) * 4);
    int*      cursor = (int*)carve((size_t)(N_NODES + 8) * 4);
    int*      bsum   = (int*)carve(1024);
    int*      elist  = (int*)carve((size_t)N_EDGES * 4);
    ushort_t* apack1 = (ushort_t*)carve((size_t)LAYERS * 32 * 8 * 64 * 8 * 2);   // 1 MB
    ushort_t* bpack2 = (ushort_t*)carve((size_t)LAYERS * 16 * 16 * 64 * 8 * 2);  // 1 MB

    const int NB = (N_NODES + SCAN_B - 1) / SCAN_B;   // 98

    // ---- one-time per call: weight pre-pack + CSR build ----
    pack1_k<<<256, 256, 0, stream>>>(W1, apack1);
    pack2_k<<<256, 256, 0, stream>>>(W2, bpack2);
    hipMemsetAsync(deg, 0, (size_t)N_NODES * 4, stream);
    count_k<<<(N_EDGES + 255) / 256, 256, 0, stream>>>(edge_index, deg);
    scan1_k<<<NB, 256, 0, stream>>>(deg, offs, bsum);
    scan2_k<<<1, 128, 0, stream>>>(bsum, NB);
    scan3_k<<<(N_NODES + 255) / 256, 256, 0, stream>>>(offs, cursor, bsum);
    fill_k<<<(N_EDGES + 255) / 256, 256, 0, stream>>>(edge_index, cursor, elist);

    encode_nodes_k<<<N_NODES, 256, 0, stream>>>(x_cat, node_emb, X);

    for (int l = 0; l < LAYERS; ++l) {
        gather_k<<<N_NODES, 256, 0, stream>>>(X, edge_emb, edge_attr, edge_index,
                                              offs, deg, elist, H);
        mlp_k<<<N_NODES / BM, 256, 0, stream>>>(
            H,
            apack1 + (size_t)l * 32 * 8 * 64 * 8,
            b1 + (size_t)l * D2,
            bpack2 + (size_t)l * 16 * 16 * 64 * 8,
            b2 + (size_t)l * D,
            X);
    }

    pool_k<<<N_GRAPHS, 256, 0, stream>>>(X, batch, G);
    final_k<<<N_GRAPHS, 256, 0, stream>>>(G, pW1, pb1, pW2, pb2, out);
}

// Round 4
// 1012.394 us; speedup vs baseline: 8.7492x; 1.4998x over previous
//
#include <hip/hip_runtime.h>

#define N_NODES 100000
#define N_NODES_PAD 100032   // 1563 * 64
#define N_EDGES 200000
#define N_GRAPHS 4096
#define D 256
#define D2 512
#define OUTD 768
#define LAYERS 4
#define NODE_FEATS 9
#define EDGE_FEATS 3
#define NODE_VOCAB 119
#define EDGE_VOCAB 22
#define BM 64            // rows per MLP block
#define GB 8             // graphs per final block

typedef __attribute__((ext_vector_type(8))) short bf16x8;
typedef __attribute__((ext_vector_type(4))) float f32x4;
typedef unsigned short ushort_t;
typedef unsigned int uint_t;

__device__ __forceinline__ ushort_t f2b(float f) {   // f32 -> bf16 bits, RNE
    union { float f; uint_t u; } x; x.f = f;
    uint_t r = (x.u + 0x7FFFu + ((x.u >> 16) & 1u)) >> 16;
    return (ushort_t)r;
}
__device__ __forceinline__ float b2f(ushort_t u) {
    union { uint_t u; float f; } x; x.u = ((uint_t)u) << 16;
    return x.f;
}

__device__ __forceinline__ int lower_bound_i(const int* a, int n, int v) {
    int lo = 0, hi = n;
    while (lo < hi) { int mid = (lo + hi) >> 1; if (a[mid] < v) lo = mid + 1; else hi = mid; }
    return lo;
}

// ---------------- embedding encode (nodes), bf16 out ----------------
__global__ __launch_bounds__(256) void encode_nodes_k(const int* __restrict__ xcat,
                                                      const float* __restrict__ tab,
                                                      ushort_t* __restrict__ X) {
    int n = blockIdx.x, d = threadIdx.x;
    float acc = 0.f;
#pragma unroll
    for (int f = 0; f < NODE_FEATS; ++f) {
        int idx = xcat[n * NODE_FEATS + f];
        acc += tab[((size_t)f * NODE_VOCAB + idx) * D + d];
    }
    X[(size_t)n * D + d] = f2b(acc);
}

// ---------------- CSR build ----------------
__global__ __launch_bounds__(256) void count_k(const int* __restrict__ eidx, int* deg) {
    int e = blockIdx.x * 256 + threadIdx.x;
    if (e < N_EDGES) atomicAdd(&deg[eidx[N_EDGES + e]], 1);
}

#define SCAN_B 1024
__global__ __launch_bounds__(256) void scan1_k(const int* __restrict__ deg,
                                               int* __restrict__ excl, int* __restrict__ bsum) {
    __shared__ int sh[256];
    int b = blockIdx.x, t = threadIdx.x;
    int base = b * SCAN_B + t * 4;
    int d0 = (base + 0) < N_NODES ? deg[base + 0] : 0;
    int d1 = (base + 1) < N_NODES ? deg[base + 1] : 0;
    int d2 = (base + 2) < N_NODES ? deg[base + 2] : 0;
    int d3 = (base + 3) < N_NODES ? deg[base + 3] : 0;
    int s = d0 + d1 + d2 + d3;
    sh[t] = s; __syncthreads();
    for (int off = 1; off < 256; off <<= 1) {
        int x = (t >= off) ? sh[t - off] : 0;
        __syncthreads();
        sh[t] += x;
        __syncthreads();
    }
    int incl = sh[t];
    int ex = incl - s;
    if (base + 0 < N_NODES) excl[base + 0] = ex;
    if (base + 1 < N_NODES) excl[base + 1] = ex + d0;
    if (base + 2 < N_NODES) excl[base + 2] = ex + d0 + d1;
    if (base + 3 < N_NODES) excl[base + 3] = ex + d0 + d1 + d2;
    if (t == 255) bsum[b] = incl;
}

__global__ void scan2_k(int* bsum, int nb) {   // 1 block of 128 threads
    __shared__ int sh[128];
    int t = threadIdx.x;
    int v = (t < nb) ? bsum[t] : 0;
    sh[t] = v; __syncthreads();
    for (int off = 1; off < 128; off <<= 1) {
        int x = (t >= off) ? sh[t - off] : 0;
        __syncthreads();
        sh[t] += x;
        __syncthreads();
    }
    if (t < nb) bsum[t] = sh[t] - v;   // exclusive over blocks
}

__global__ __launch_bounds__(256) void scan3_k(int* __restrict__ offs, int* __restrict__ cursor,
                                               const int* __restrict__ bsum) {
    int i = blockIdx.x * 256 + threadIdx.x;
    if (i < N_NODES) {
        int v = offs[i] + bsum[i >> 10];
        offs[i] = v;
        cursor[i] = v;
    }
}

__global__ __launch_bounds__(256) void fill_k(const int* __restrict__ eidx,
                                              int* cursor, int* __restrict__ elist) {
    int e = blockIdx.x * 256 + threadIdx.x;
    if (e < N_EDGES) {
        int pos = atomicAdd(&cursor[eidx[N_EDGES + e]], 1);
        elist[pos] = e;
    }
}

// -------- gather aggregation: H = bf16(X[n] + sum relu(X[src]+e_emb)), 4 nodes/block -----
__global__ __launch_bounds__(256) void gather_k(const ushort4* __restrict__ X4,
                                                const float4* __restrict__ eemb4,
                                                const int* __restrict__ eattr,
                                                const int* __restrict__ eidx,
                                                const int* __restrict__ offs,
                                                const int* __restrict__ deg,
                                                const int* __restrict__ elist,
                                                ushort4* __restrict__ H4) {
    int n = blockIdx.x * 4 + (threadIdx.x >> 6);
    int lane = threadIdx.x & 63;
    int start = offs[n], dg = deg[n];
    ushort4 xv = X4[(size_t)n * 64 + lane];
    float acc[4] = {b2f(xv.x), b2f(xv.y), b2f(xv.z), b2f(xv.w)};
    for (int i = 0; i < dg; ++i) {
        int e = elist[start + i];
        int src = eidx[e];
        ushort4 sv = X4[(size_t)src * 64 + lane];
        float ev[4] = {0.f, 0.f, 0.f, 0.f};
#pragma unroll
        for (int f = 0; f < EDGE_FEATS; ++f) {
            int idx = eattr[e * EDGE_FEATS + f];
            float4 tv = eemb4[((size_t)f * EDGE_VOCAB + idx) * 64 + lane];
            ev[0] += tv.x; ev[1] += tv.y; ev[2] += tv.z; ev[3] += tv.w;
        }
        acc[0] += fmaxf(b2f(sv.x) + ev[0], 0.f);
        acc[1] += fmaxf(b2f(sv.y) + ev[1], 0.f);
        acc[2] += fmaxf(b2f(sv.z) + ev[2], 0.f);
        acc[3] += fmaxf(b2f(sv.w) + ev[3], 0.f);
    }
    ushort4 hv;
    hv.x = f2b(acc[0]); hv.y = f2b(acc[1]); hv.z = f2b(acc[2]); hv.w = f2b(acc[3]);
    H4[(size_t)n * 64 + lane] = hv;
}

// ---------------- weight pre-pack into MFMA fragment layout (bf16) ----------------
// apack1[l][ntg(32)][kk(8)][lane(64)][j(8)] = W1[l][kk*32+(lane>>4)*8+j][ntg*16+(lane&15)]
__global__ __launch_bounds__(256) void pack1_k(const float* __restrict__ W1, ushort_t* __restrict__ apack) {
    size_t i = (size_t)blockIdx.x * 256 + threadIdx.x;   // 65536 groups
    int l = (int)(i >> 14);
    int rem = (int)(i & 16383);
    int ntg = rem >> 9;
    int rem2 = rem & 511;
    int kk = rem2 >> 6;
    int lane = rem2 & 63;
    int n = ntg * 16 + (lane & 15);
    int k0 = kk * 32 + (lane >> 4) * 8;
    const float* w = W1 + ((size_t)l * D + k0) * D2 + n;
    ushort_t* o = apack + i * 8;
#pragma unroll
    for (int j = 0; j < 8; ++j) o[j] = f2b(w[(size_t)j * D2]);
}

// bpack2[l][ntg(16)][kk(16)][lane(64)][j(8)] = W2[l][kk*32+(lane>>4)*8+j][ntg*16+(lane&15)]
__global__ __launch_bounds__(256) void pack2_k(const float* __restrict__ W2, ushort_t* __restrict__ bpack) {
    size_t i = (size_t)blockIdx.x * 256 + threadIdx.x;   // 65536 groups
    int l = (int)(i >> 14);
    int rem = (int)(i & 16383);
    int ntg = rem >> 10;
    int rem2 = rem & 1023;
    int kk = rem2 >> 6;
    int lane = rem2 & 63;
    int n = ntg * 16 + (lane & 15);
    int k0 = kk * 32 + (lane >> 4) * 8;
    const float* w = W2 + ((size_t)l * D2 + k0) * D + n;
    ushort_t* o = bpack + i * 8;
#pragma unroll
    for (int j = 0; j < 8; ++j) o[j] = f2b(w[(size_t)j * D]);
}

// ---------------- fused MFMA MLP: X = relu(relu(H@W1+b1)@W2+b2), BM=64, split-k G2 ------
// 4 waves; wave owns n-quarter. mid processed in two 256-col halves through one 32KB buf.
__global__ __launch_bounds__(256, 2) void mlp_k(const ushort_t* __restrict__ H,
                                                const ushort_t* __restrict__ apack,
                                                const float* __restrict__ b1,
                                                const ushort_t* __restrict__ bpack,
                                                const float* __restrict__ b2,
                                                ushort_t* __restrict__ X) {
    __shared__ __align__(16) char hA[BM * 512];    // 32KB: 64 rows x 256 bf16, swizzled
    __shared__ __align__(16) char midh[BM * 512];  // 32KB: 64 rows x 256 bf16 (one n-half)
    const int t = threadIdx.x;
    const int wid = t >> 6, lane = t & 63;
    const int l15 = lane & 15, g = lane >> 4;
    const size_t r0 = (size_t)blockIdx.x * BM;

    // ---- stage H tile (64 rows, 32KB) with XOR swizzle ----
    {
        const char* src = (const char*)(H + r0 * D);
#pragma unroll
        for (int c = 0; c < 8; ++c) {
            int Lb = (c * 256 + t) * 16;
            int row = Lb >> 9;
            int Sb = Lb ^ ((row & 7) << 4);
            *(uint4*)(hA + Sb) = *(const uint4*)(src + Lb);
        }
    }
    __syncthreads();

    f32x4 acc2[4][4];
#pragma unroll
    for (int a = 0; a < 4; ++a)
#pragma unroll
        for (int b = 0; b < 4; ++b) { f32x4 z = {0.f,0.f,0.f,0.f}; acc2[a][b] = z; }

#pragma unroll
    for (int half = 0; half < 2; ++half) {
        // ---- GEMM1 half (transposed): mid[:, half*256 .. +256) ----
        f32x4 acc1[4][4];
#pragma unroll
        for (int a = 0; a < 4; ++a)
#pragma unroll
            for (int b = 0; b < 4; ++b) { f32x4 z = {0.f,0.f,0.f,0.f}; acc1[a][b] = z; }
#pragma unroll
        for (int kk = 0; kk < 8; ++kk) {
            bf16x8 Bf[4];
#pragma unroll
            for (int mt = 0; mt < 4; ++mt) {
                int m = mt * 16 + l15;
                int byte_ = (m * 512 + (kk * 32 + g * 8) * 2) ^ ((m & 7) << 4);
                Bf[mt] = *(const bf16x8*)(hA + byte_);
            }
#pragma unroll
            for (int nt = 0; nt < 4; ++nt) {
                int ntg = half * 16 + wid * 4 + nt;
                bf16x8 Af = *(const bf16x8*)(apack + ((size_t)(ntg * 8 + kk) * 64 + lane) * 8);
#pragma unroll
                for (int mt = 0; mt < 4; ++mt)
                    acc1[nt][mt] = __builtin_amdgcn_mfma_f32_16x16x32_bf16(Af, Bf[mt], acc1[nt][mt], 0, 0, 0);
            }
        }
        // bias + relu + pack to midh (lane holds 4 consecutive n at fixed m)
#pragma unroll
        for (int nt = 0; nt < 4; ++nt) {
            int ntl = wid * 4 + nt;                 // local n-tile within half
            int n0l = ntl * 16 + g * 4;             // local col
            f32x4 bv = *(const f32x4*)(b1 + half * 256 + n0l);
#pragma unroll
            for (int mt = 0; mt < 4; ++mt) {
                int m = mt * 16 + l15;
                ushort_t us[4];
#pragma unroll
                for (int r = 0; r < 4; ++r)
                    us[r] = f2b(fmaxf(acc1[nt][mt][r] + bv[r], 0.f));
                uint2 pk;
                pk.x = (uint_t)us[0] | ((uint_t)us[1] << 16);
                pk.y = (uint_t)us[2] | ((uint_t)us[3] << 16);
                int byte_ = (m * 512 + n0l * 2) ^ ((m & 7) << 4);
                *(uint2*)(midh + byte_) = pk;
            }
        }
        __syncthreads();

        // ---- GEMM2 partial (transposed): acc2 += mid_half @ W2[k-half] ----
#pragma unroll
        for (int kk = 0; kk < 8; ++kk) {
            bf16x8 Mf[4];
#pragma unroll
            for (int mt = 0; mt < 4; ++mt) {
                int m = mt * 16 + l15;
                int byte_ = (m * 512 + (kk * 32 + g * 8) * 2) ^ ((m & 7) << 4);
                Mf[mt] = *(const bf16x8*)(midh + byte_);
            }
#pragma unroll
            for (int nt = 0; nt < 4; ++nt) {
                int ntg = wid * 4 + nt;
                int kkg = half * 8 + kk;
                bf16x8 Wf = *(const bf16x8*)(bpack + ((size_t)(ntg * 16 + kkg) * 64 + lane) * 8);
#pragma unroll
                for (int mt = 0; mt < 4; ++mt)
                    acc2[nt][mt] = __builtin_amdgcn_mfma_f32_16x16x32_bf16(Wf, Mf[mt], acc2[nt][mt], 0, 0, 0);
            }
        }
        __syncthreads();   // all reads of midh done before next half overwrites
    }

    // ---- epilogue GEMM2: D[row=n][col=m]; lane holds 4 consecutive n at fixed m ----
#pragma unroll
    for (int nt = 0; nt < 4; ++nt) {
        int n0 = (wid * 4 + nt) * 16 + g * 4;
        f32x4 bv = *(const f32x4*)(b2 + n0);
#pragma unroll
        for (int mt = 0; mt < 4; ++mt) {
            int m = mt * 16 + l15;
            ushort_t us[4];
#pragma unroll
            for (int r = 0; r < 4; ++r)
                us[r] = f2b(fmaxf(acc2[nt][mt][r] + bv[r], 0.f));
            uint2 pk;
            pk.x = (uint_t)us[0] | ((uint_t)us[1] << 16);
            pk.y = (uint_t)us[2] | ((uint_t)us[3] << 16);
            *(uint2*)(X + (r0 + m) * D + n0) = pk;
        }
    }
}

// -------- fused pooling + final MLP + L2 normalize, GB=8 graphs per block --------
__global__ __launch_bounds__(256) void final_k(const ushort_t* __restrict__ X,
                                               const int* __restrict__ batch,
                                               const float* __restrict__ pW1,
                                               const float* __restrict__ pb1,
                                               const float* __restrict__ pW2,
                                               const float* __restrict__ pb2,
                                               float* __restrict__ out) {
    __shared__ float gin[GB][D];    // 8KB
    __shared__ float mid[GB][D];    // 8KB
    __shared__ float red[GB][256];  // 8KB
    __shared__ int bnd[GB + 1];
    const int g0 = blockIdx.x * GB, t = threadIdx.x;
    if (t <= GB) bnd[t] = lower_bound_i(batch, N_NODES, g0 + t);
    __syncthreads();

    // pooling: gin[q][t] = sum of X rows of graph q (bf16 -> f32)
#pragma unroll
    for (int q = 0; q < GB; ++q) {
        float a = 0.f;
        for (int n = bnd[q]; n < bnd[q + 1]; ++n)
            a += b2f(X[(size_t)n * D + t]);
        gin[q][t] = a;
    }
    __syncthreads();

    // mlp1: mid = relu(gin @ pW1 + pb1)
    {
        float m_[GB];
        float bb = pb1[t];
#pragma unroll
        for (int q = 0; q < GB; ++q) m_[q] = bb;
        for (int k = 0; k < D; ++k) {
            float w = pW1[(size_t)k * D + t];
#pragma unroll
            for (int q = 0; q < GB; ++q) m_[q] += gin[q][k] * w;
        }
#pragma unroll
        for (int q = 0; q < GB; ++q) mid[q][t] = fmaxf(m_[q], 0.f);
    }
    __syncthreads();

    // mlp2 + norm
    float a0[GB], a1[GB], a2[GB];
    {
        float b0 = pb2[t], b1_ = pb2[t + 256], b2_ = pb2[t + 512];
#pragma unroll
        for (int q = 0; q < GB; ++q) { a0[q] = b0; a1[q] = b1_; a2[q] = b2_; }
        for (int k = 0; k < D; ++k) {
            float w0 = pW2[(size_t)k * OUTD + t];
            float w1 = pW2[(size_t)k * OUTD + 256 + t];
            float w2 = pW2[(size_t)k * OUTD + 512 + t];
#pragma unroll
            for (int q = 0; q < GB; ++q) {
                float mv = mid[q][k];
                a0[q] += mv * w0; a1[q] += mv * w1; a2[q] += mv * w2;
            }
        }
    }
#pragma unroll
    for (int q = 0; q < GB; ++q)
        red[q][t] = a0[q] * a0[q] + a1[q] * a1[q] + a2[q] * a2[q];
    __syncthreads();
    for (int s = 128; s > 0; s >>= 1) {
        if (t < s) {
#pragma unroll
            for (int q = 0; q < GB; ++q) red[q][t] += red[q][t + s];
        }
        __syncthreads();
    }
#pragma unroll
    for (int q = 0; q < GB; ++q) {
        float inv = 1.f / fmaxf(sqrtf(red[q][0]), 1e-12f);
        out[(size_t)(g0 + q) * OUTD + t]       = a0[q] * inv;
        out[(size_t)(g0 + q) * OUTD + 256 + t] = a1[q] * inv;
        out[(size_t)(g0 + q) * OUTD + 512 + t] = a2[q] * inv;
    }
}

extern "C" void kernel_launch(void* const* d_in, const int* in_sizes, int n_in,
                              void* d_out, int out_size, void* d_ws, size_t ws_size,
                              hipStream_t stream) {
    const int*   x_cat      = (const int*)d_in[0];
    const int*   edge_attr  = (const int*)d_in[1];
    const int*   edge_index = (const int*)d_in[2];
    const int*   batch      = (const int*)d_in[3];
    const float* node_emb   = (const float*)d_in[4];
    const float* edge_emb   = (const float*)d_in[5];
    const float* W1  = (const float*)d_in[6];
    const float* b1  = (const float*)d_in[7];
    const float* W2  = (const float*)d_in[8];
    const float* b2  = (const float*)d_in[9];
    const float* pW1 = (const float*)d_in[10];
    const float* pb1 = (const float*)d_in[11];
    const float* pW2 = (const float*)d_in[12];
    const float* pb2 = (const float*)d_in[13];
    float* out = (float*)d_out;

    // ---- workspace carve (~110 MB) ----
    char* p = (char*)d_ws;
    auto carve = [&](size_t bytes) { char* q = p; p += (bytes + 255) & ~(size_t)255; return q; };
    ushort_t* X      = (ushort_t*)carve((size_t)N_NODES_PAD * D * 2);   // 51.2 MB
    ushort_t* H      = (ushort_t*)carve((size_t)N_NODES_PAD * D * 2);   // 51.2 MB
    int*      deg    = (int*)carve((size_t)N_NODES * 4);
    int*      offs   = (int*)carve((size_t)(N_NODES + 8) * 4);
    int*      cursor = (int*)carve((size_t)(N_NODES + 8) * 4);
    int*      bsum   = (int*)carve(1024);
    int*      elist  = (int*)carve((size_t)N_EDGES * 4);
    ushort_t* apack1 = (ushort_t*)carve((size_t)LAYERS * 32 * 8 * 64 * 8 * 2);   // 2 MB
    ushort_t* bpack2 = (ushort_t*)carve((size_t)LAYERS * 16 * 16 * 64 * 8 * 2);  // 2 MB

    const int NB = (N_NODES + SCAN_B - 1) / SCAN_B;   // 98

    // ---- one-time per call: weight pre-pack + CSR build ----
    pack1_k<<<256, 256, 0, stream>>>(W1, apack1);
    pack2_k<<<256, 256, 0, stream>>>(W2, bpack2);
    hipMemsetAsync(deg, 0, (size_t)N_NODES * 4, stream);
    count_k<<<(N_EDGES + 255) / 256, 256, 0, stream>>>(edge_index, deg);
    scan1_k<<<NB, 256, 0, stream>>>(deg, offs, bsum);
    scan2_k<<<1, 128, 0, stream>>>(bsum, NB);
    scan3_k<<<(N_NODES + 255) / 256, 256, 0, stream>>>(offs, cursor, bsum);
    fill_k<<<(N_EDGES + 255) / 256, 256, 0, stream>>>(edge_index, cursor, elist);

    encode_nodes_k<<<N_NODES, 256, 0, stream>>>(x_cat, node_emb, X);

    for (int l = 0; l < LAYERS; ++l) {
        gather_k<<<N_NODES / 4, 256, 0, stream>>>((const ushort4*)X, (const float4*)edge_emb,
                                                  edge_attr, edge_index, offs, deg, elist,
                                                  (ushort4*)H);
        mlp_k<<<(N_NODES + BM - 1) / BM, 256, 0, stream>>>(
            H,
            apack1 + (size_t)l * 32 * 8 * 64 * 8,
            b1 + (size_t)l * D2,
            bpack2 + (size_t)l * 16 * 16 * 64 * 8,
            b2 + (size_t)l * D,
            X);
    }

    final_k<<<N_GRAPHS / GB, 256, 0, stream>>>(X, batch, pW1, pb1, pW2, pb2, out);
}

// Round 5
// 751.181 us; speedup vs baseline: 11.7916x; 1.3477x over previous
//
#include <hip/hip_runtime.h>

#define N_NODES 100000
#define N_NODES_PAD 100032   // 1563 * 64
#define N_EDGES 200000
#define N_GRAPHS 4096
#define D 256
#define D2 512
#define OUTD 768
#define LAYERS 4
#define NODE_FEATS 9
#define EDGE_FEATS 3
#define NODE_VOCAB 119
#define EDGE_VOCAB 22
#define BM 64            // rows per MLP block
#define GB 8             // graphs per final block

typedef __attribute__((ext_vector_type(8))) short bf16x8;
typedef __attribute__((ext_vector_type(4))) float f32x4;
typedef unsigned short ushort_t;
typedef unsigned int uint_t;

__device__ __forceinline__ ushort_t f2b(float f) {   // f32 -> bf16 bits, RNE
    union { float f; uint_t u; } x; x.f = f;
    uint_t r = (x.u + 0x7FFFu + ((x.u >> 16) & 1u)) >> 16;
    return (ushort_t)r;
}
__device__ __forceinline__ float b2f(ushort_t u) {
    union { uint_t u; float f; } x; x.u = ((uint_t)u) << 16;
    return x.f;
}

__device__ __forceinline__ int lower_bound_i(const int* a, int n, int v) {
    int lo = 0, hi = n;
    while (lo < hi) { int mid = (lo + hi) >> 1; if (a[mid] < v) lo = mid + 1; else hi = mid; }
    return lo;
}

// ---------------- embedding encode (nodes), bf16 out ----------------
__global__ __launch_bounds__(256) void encode_nodes_k(const int* __restrict__ xcat,
                                                      const float* __restrict__ tab,
                                                      ushort_t* __restrict__ X) {
    int n = blockIdx.x, d = threadIdx.x;
    float acc = 0.f;
#pragma unroll
    for (int f = 0; f < NODE_FEATS; ++f) {
        int idx = xcat[n * NODE_FEATS + f];
        acc += tab[((size_t)f * NODE_VOCAB + idx) * D + d];
    }
    X[(size_t)n * D + d] = f2b(acc);
}

// ---------------- CSR build ----------------
__global__ __launch_bounds__(256) void count_k(const int* __restrict__ eidx, int* deg) {
    int e = blockIdx.x * 256 + threadIdx.x;
    if (e < N_EDGES) atomicAdd(&deg[eidx[N_EDGES + e]], 1);
}

#define SCAN_B 1024
__global__ __launch_bounds__(256) void scan1_k(const int* __restrict__ deg,
                                               int* __restrict__ excl, int* __restrict__ bsum) {
    __shared__ int sh[256];
    int b = blockIdx.x, t = threadIdx.x;
    int base = b * SCAN_B + t * 4;
    int d0 = (base + 0) < N_NODES ? deg[base + 0] : 0;
    int d1 = (base + 1) < N_NODES ? deg[base + 1] : 0;
    int d2 = (base + 2) < N_NODES ? deg[base + 2] : 0;
    int d3 = (base + 3) < N_NODES ? deg[base + 3] : 0;
    int s = d0 + d1 + d2 + d3;
    sh[t] = s; __syncthreads();
    for (int off = 1; off < 256; off <<= 1) {
        int x = (t >= off) ? sh[t - off] : 0;
        __syncthreads();
        sh[t] += x;
        __syncthreads();
    }
    int incl = sh[t];
    int ex = incl - s;
    if (base + 0 < N_NODES) excl[base + 0] = ex;
    if (base + 1 < N_NODES) excl[base + 1] = ex + d0;
    if (base + 2 < N_NODES) excl[base + 2] = ex + d0 + d1;
    if (base + 3 < N_NODES) excl[base + 3] = ex + d0 + d1 + d2;
    if (t == 255) bsum[b] = incl;
}

__global__ void scan2_k(int* bsum, int nb) {   // 1 block of 128 threads
    __shared__ int sh[128];
    int t = threadIdx.x;
    int v = (t < nb) ? bsum[t] : 0;
    sh[t] = v; __syncthreads();
    for (int off = 1; off < 128; off <<= 1) {
        int x = (t >= off) ? sh[t - off] : 0;
        __syncthreads();
        sh[t] += x;
        __syncthreads();
    }
    if (t < nb) bsum[t] = sh[t] - v;   // exclusive over blocks
}

__global__ __launch_bounds__(256) void scan3_k(int* __restrict__ offs, int* __restrict__ cursor,
                                               const int* __restrict__ bsum) {
    int i = blockIdx.x * 256 + threadIdx.x;
    if (i < N_NODES) {
        int v = offs[i] + bsum[i >> 10];
        offs[i] = v;
        cursor[i] = v;
    }
}

// elist entry: {src node, packed edge attrs} -- kills the e->eidx/eattr dependent loads
__global__ __launch_bounds__(256) void fill_k(const int* __restrict__ eidx,
                                              const int* __restrict__ eattr,
                                              int* cursor, int2* __restrict__ elist) {
    int e = blockIdx.x * 256 + threadIdx.x;
    if (e < N_EDGES) {
        int src = eidx[e];
        int dst = eidx[N_EDGES + e];
        int pa = eattr[e * EDGE_FEATS + 0] | (eattr[e * EDGE_FEATS + 1] << 8)
               | (eattr[e * EDGE_FEATS + 2] << 16);
        int pos = atomicAdd(&cursor[dst], 1);
        elist[pos] = make_int2(src, pa);
    }
}

// -------- gather aggregation: H = bf16(X[n] + sum relu(X[src]+e_emb)), 4 nodes/block -----
__global__ __launch_bounds__(256) void gather_k(const ushort4* __restrict__ X4,
                                                const float4* __restrict__ eemb4,
                                                const int* __restrict__ offs,
                                                const int* __restrict__ deg,
                                                const int2* __restrict__ elist,
                                                ushort4* __restrict__ H4) {
    int n = blockIdx.x * 4 + (threadIdx.x >> 6);
    int lane = threadIdx.x & 63;
    int start = offs[n], dg = deg[n];
    ushort4 xv = X4[(size_t)n * 64 + lane];
    float acc[4] = {b2f(xv.x), b2f(xv.y), b2f(xv.z), b2f(xv.w)};
    for (int i = 0; i < dg; ++i) {
        int2 sp = elist[start + i];
        ushort4 sv = X4[(size_t)sp.x * 64 + lane];
        float4 t0 = eemb4[(size_t)((sp.y      ) & 255) * 64 + lane];
        float4 t1 = eemb4[((size_t)EDGE_VOCAB + ((sp.y >> 8) & 255)) * 64 + lane];
        float4 t2 = eemb4[((size_t)2 * EDGE_VOCAB + ((sp.y >> 16) & 255)) * 64 + lane];
        acc[0] += fmaxf(b2f(sv.x) + t0.x + t1.x + t2.x, 0.f);
        acc[1] += fmaxf(b2f(sv.y) + t0.y + t1.y + t2.y, 0.f);
        acc[2] += fmaxf(b2f(sv.z) + t0.z + t1.z + t2.z, 0.f);
        acc[3] += fmaxf(b2f(sv.w) + t0.w + t1.w + t2.w, 0.f);
    }
    ushort4 hv;
    hv.x = f2b(acc[0]); hv.y = f2b(acc[1]); hv.z = f2b(acc[2]); hv.w = f2b(acc[3]);
    H4[(size_t)n * 64 + lane] = hv;
}

// ---------------- weight pre-pack into MFMA fragment layout (bf16) ----------------
// apack1[l][ntg(32)][kk(8)][lane(64)][j(8)] = W1[l][kk*32+(lane>>4)*8+j][ntg*16+(lane&15)]
__global__ __launch_bounds__(256) void pack1_k(const float* __restrict__ W1, ushort_t* __restrict__ apack) {
    size_t i = (size_t)blockIdx.x * 256 + threadIdx.x;   // 65536 groups
    int l = (int)(i >> 14);
    int rem = (int)(i & 16383);
    int ntg = rem >> 9;
    int rem2 = rem & 511;
    int kk = rem2 >> 6;
    int lane = rem2 & 63;
    int n = ntg * 16 + (lane & 15);
    int k0 = kk * 32 + (lane >> 4) * 8;
    const float* w = W1 + ((size_t)l * D + k0) * D2 + n;
    ushort_t* o = apack + i * 8;
#pragma unroll
    for (int j = 0; j < 8; ++j) o[j] = f2b(w[(size_t)j * D2]);
}

// bpack2[l][ntg(16)][kk(16)][lane(64)][j(8)] = W2[l][kk*32+(lane>>4)*8+j][ntg*16+(lane&15)]
__global__ __launch_bounds__(256) void pack2_k(const float* __restrict__ W2, ushort_t* __restrict__ bpack) {
    size_t i = (size_t)blockIdx.x * 256 + threadIdx.x;   // 65536 groups
    int l = (int)(i >> 14);
    int rem = (int)(i & 16383);
    int ntg = rem >> 10;
    int rem2 = rem & 1023;
    int kk = rem2 >> 6;
    int lane = rem2 & 63;
    int n = ntg * 16 + (lane & 15);
    int k0 = kk * 32 + (lane >> 4) * 8;
    const float* w = W2 + ((size_t)l * D2 + k0) * D + n;
    ushort_t* o = bpack + i * 8;
#pragma unroll
    for (int j = 0; j < 8; ++j) o[j] = f2b(w[(size_t)j * D]);
}

// ---------------- fused MFMA MLP: X = relu(relu(H@W1+b1)@W2+b2) ----------------
// 512 threads = 8 waves, BM=64 rows, 64KB LDS -> 2 blocks/CU = 4 waves/SIMD.
// Wave owns a 32-col n-slice in each GEMM; regs <= 128 via launch_bounds(512,4).
__global__ __launch_bounds__(512, 4) void mlp_k(const ushort_t* __restrict__ H,
                                                const ushort_t* __restrict__ apack,
                                                const float* __restrict__ b1,
                                                const ushort_t* __restrict__ bpack,
                                                const float* __restrict__ b2,
                                                ushort_t* __restrict__ X) {
    __shared__ __align__(16) char hA[BM * 512];    // 32KB: 64 rows x 256 bf16, swizzled
    __shared__ __align__(16) char midh[BM * 512];  // 32KB: 64 rows x 256 bf16 (one n-half)
    const int t = threadIdx.x;
    const int wid = t >> 6, lane = t & 63;
    const int l15 = lane & 15, g = lane >> 4;
    const size_t r0 = (size_t)blockIdx.x * BM;

    // ---- stage H tile (64 rows, 32KB) with XOR swizzle ----
    {
        const char* src = (const char*)(H + r0 * D);
#pragma unroll
        for (int c = 0; c < 4; ++c) {
            int Lb = (c * 512 + t) * 16;
            int row = Lb >> 9;
            int Sb = Lb ^ ((row & 7) << 4);
            *(uint4*)(hA + Sb) = *(const uint4*)(src + Lb);
        }
    }
    __syncthreads();

    f32x4 acc2[2][4];
#pragma unroll
    for (int a = 0; a < 2; ++a)
#pragma unroll
        for (int b = 0; b < 4; ++b) { f32x4 z = {0.f,0.f,0.f,0.f}; acc2[a][b] = z; }

#pragma unroll
    for (int half = 0; half < 2; ++half) {
        // ---- GEMM1 (transposed): mid[:, half*256 + wid*32 + nt*16 ...] ----
        f32x4 acc1[2][4];
#pragma unroll
        for (int a = 0; a < 2; ++a)
#pragma unroll
            for (int b = 0; b < 4; ++b) { f32x4 z = {0.f,0.f,0.f,0.f}; acc1[a][b] = z; }

        bf16x8 AfA[2], AfB[2];
#pragma unroll
        for (int nt = 0; nt < 2; ++nt)
            AfA[nt] = *(const bf16x8*)(apack +
                ((size_t)((half * 16 + wid * 2 + nt) * 8 + 0) * 64 + lane) * 8);
#pragma unroll
        for (int kk = 0; kk < 8; ++kk) {
            bf16x8 Bf[4];
#pragma unroll
            for (int mt = 0; mt < 4; ++mt) {
                int m = mt * 16 + l15;
                Bf[mt] = *(const bf16x8*)(hA + ((m * 512 + (kk * 32 + g * 8) * 2) ^ ((m & 7) << 4)));
            }
            bf16x8* cur = (kk & 1) ? AfB : AfA;   // kk is compile-time under unroll
            bf16x8* nxt = (kk & 1) ? AfA : AfB;
            if (kk < 7) {
#pragma unroll
                for (int nt = 0; nt < 2; ++nt)
                    nxt[nt] = *(const bf16x8*)(apack +
                        ((size_t)((half * 16 + wid * 2 + nt) * 8 + kk + 1) * 64 + lane) * 8);
            }
#pragma unroll
            for (int nt = 0; nt < 2; ++nt)
#pragma unroll
                for (int mt = 0; mt < 4; ++mt)
                    acc1[nt][mt] = __builtin_amdgcn_mfma_f32_16x16x32_bf16(cur[nt], Bf[mt], acc1[nt][mt], 0, 0, 0);
        }
        // bias + relu + pack to midh (lane holds 4 consecutive n at fixed m)
#pragma unroll
        for (int nt = 0; nt < 2; ++nt) {
            int n0l = (wid * 2 + nt) * 16 + g * 4;             // local col in half
            f32x4 bv = *(const f32x4*)(b1 + half * 256 + n0l);
#pragma unroll
            for (int mt = 0; mt < 4; ++mt) {
                int m = mt * 16 + l15;
                ushort_t us[4];
#pragma unroll
                for (int r = 0; r < 4; ++r)
                    us[r] = f2b(fmaxf(acc1[nt][mt][r] + bv[r], 0.f));
                uint2 pk;
                pk.x = (uint_t)us[0] | ((uint_t)us[1] << 16);
                pk.y = (uint_t)us[2] | ((uint_t)us[3] << 16);
                *(uint2*)(midh + ((m * 512 + n0l * 2) ^ ((m & 7) << 4))) = pk;
            }
        }
        __syncthreads();   // midh fully written

        // ---- GEMM2 partial (transposed): acc2 += mid_half @ W2[k-half] ----
        bf16x8 WfA[2], WfB[2];
#pragma unroll
        for (int nt = 0; nt < 2; ++nt)
            WfA[nt] = *(const bf16x8*)(bpack +
                ((size_t)((wid * 2 + nt) * 16 + half * 8 + 0) * 64 + lane) * 8);
#pragma unroll
        for (int kk = 0; kk < 8; ++kk) {
            bf16x8 Mf[4];
#pragma unroll
            for (int mt = 0; mt < 4; ++mt) {
                int m = mt * 16 + l15;
                Mf[mt] = *(const bf16x8*)(midh + ((m * 512 + (kk * 32 + g * 8) * 2) ^ ((m & 7) << 4)));
            }
            bf16x8* cur = (kk & 1) ? WfB : WfA;
            bf16x8* nxt = (kk & 1) ? WfA : WfB;
            if (kk < 7) {
#pragma unroll
                for (int nt = 0; nt < 2; ++nt)
                    nxt[nt] = *(const bf16x8*)(bpack +
                        ((size_t)((wid * 2 + nt) * 16 + half * 8 + kk + 1) * 64 + lane) * 8);
            }
#pragma unroll
            for (int nt = 0; nt < 2; ++nt)
#pragma unroll
                for (int mt = 0; mt < 4; ++mt)
                    acc2[nt][mt] = __builtin_amdgcn_mfma_f32_16x16x32_bf16(cur[nt], Mf[mt], acc2[nt][mt], 0, 0, 0);
        }
        __syncthreads();   // all reads of midh done before next half overwrites
    }

    // ---- epilogue GEMM2: lane holds 4 consecutive n at fixed m ----
#pragma unroll
    for (int nt = 0; nt < 2; ++nt) {
        int n0 = (wid * 2 + nt) * 16 + g * 4;
        f32x4 bv = *(const f32x4*)(b2 + n0);
#pragma unroll
        for (int mt = 0; mt < 4; ++mt) {
            int m = mt * 16 + l15;
            ushort_t us[4];
#pragma unroll
            for (int r = 0; r < 4; ++r)
                us[r] = f2b(fmaxf(acc2[nt][mt][r] + bv[r], 0.f));
            uint2 pk;
            pk.x = (uint_t)us[0] | ((uint_t)us[1] << 16);
            pk.y = (uint_t)us[2] | ((uint_t)us[3] << 16);
            *(uint2*)(X + (r0 + m) * D + n0) = pk;
        }
    }
}

// -------- fused pooling + final MLP + L2 normalize, GB=8 graphs per block --------
__global__ __launch_bounds__(256) void final_k(const ushort_t* __restrict__ X,
                                               const int* __restrict__ batch,
                                               const float* __restrict__ pW1,
                                               const float* __restrict__ pb1,
                                               const float* __restrict__ pW2,
                                               const float* __restrict__ pb2,
                                               float* __restrict__ out) {
    __shared__ float gin[GB][D];    // 8KB
    __shared__ float mid[GB][D];    // 8KB
    __shared__ float red[GB][256];  // 8KB
    __shared__ int bnd[GB + 1];
    const int g0 = blockIdx.x * GB, t = threadIdx.x;
    if (t <= GB) bnd[t] = lower_bound_i(batch, N_NODES, g0 + t);
    __syncthreads();

#pragma unroll
    for (int q = 0; q < GB; ++q) {
        float a = 0.f;
        for (int n = bnd[q]; n < bnd[q + 1]; ++n)
            a += b2f(X[(size_t)n * D + t]);
        gin[q][t] = a;
    }
    __syncthreads();

    {
        float m_[GB];
        float bb = pb1[t];
#pragma unroll
        for (int q = 0; q < GB; ++q) m_[q] = bb;
        for (int k = 0; k < D; ++k) {
            float w = pW1[(size_t)k * D + t];
#pragma unroll
            for (int q = 0; q < GB; ++q) m_[q] += gin[q][k] * w;
        }
#pragma unroll
        for (int q = 0; q < GB; ++q) mid[q][t] = fmaxf(m_[q], 0.f);
    }
    __syncthreads();

    float a0[GB], a1[GB], a2[GB];
    {
        float b0 = pb2[t], b1_ = pb2[t + 256], b2_ = pb2[t + 512];
#pragma unroll
        for (int q = 0; q < GB; ++q) { a0[q] = b0; a1[q] = b1_; a2[q] = b2_; }
        for (int k = 0; k < D; ++k) {
            float w0 = pW2[(size_t)k * OUTD + t];
            float w1 = pW2[(size_t)k * OUTD + 256 + t];
            float w2 = pW2[(size_t)k * OUTD + 512 + t];
#pragma unroll
            for (int q = 0; q < GB; ++q) {
                float mv = mid[q][k];
                a0[q] += mv * w0; a1[q] += mv * w1; a2[q] += mv * w2;
            }
        }
    }
#pragma unroll
    for (int q = 0; q < GB; ++q)
        red[q][t] = a0[q] * a0[q] + a1[q] * a1[q] + a2[q] * a2[q];
    __syncthreads();
    for (int s = 128; s > 0; s >>= 1) {
        if (t < s) {
#pragma unroll
            for (int q = 0; q < GB; ++q) red[q][t] += red[q][t + s];
        }
        __syncthreads();
    }
#pragma unroll
    for (int q = 0; q < GB; ++q) {
        float inv = 1.f / fmaxf(sqrtf(red[q][0]), 1e-12f);
        out[(size_t)(g0 + q) * OUTD + t]       = a0[q] * inv;
        out[(size_t)(g0 + q) * OUTD + 256 + t] = a1[q] * inv;
        out[(size_t)(g0 + q) * OUTD + 512 + t] = a2[q] * inv;
    }
}

extern "C" void kernel_launch(void* const* d_in, const int* in_sizes, int n_in,
                              void* d_out, int out_size, void* d_ws, size_t ws_size,
                              hipStream_t stream) {
    const int*   x_cat      = (const int*)d_in[0];
    const int*   edge_attr  = (const int*)d_in[1];
    const int*   edge_index = (const int*)d_in[2];
    const int*   batch      = (const int*)d_in[3];
    const float* node_emb   = (const float*)d_in[4];
    const float* edge_emb   = (const float*)d_in[5];
    const float* W1  = (const float*)d_in[6];
    const float* b1  = (const float*)d_in[7];
    const float* W2  = (const float*)d_in[8];
    const float* b2  = (const float*)d_in[9];
    const float* pW1 = (const float*)d_in[10];
    const float* pb1 = (const float*)d_in[11];
    const float* pW2 = (const float*)d_in[12];
    const float* pb2 = (const float*)d_in[13];
    float* out = (float*)d_out;

    // ---- workspace carve (~112 MB) ----
    char* p = (char*)d_ws;
    auto carve = [&](size_t bytes) { char* q = p; p += (bytes + 255) & ~(size_t)255; return q; };
    ushort_t* X      = (ushort_t*)carve((size_t)N_NODES_PAD * D * 2);   // 51.2 MB
    ushort_t* H      = (ushort_t*)carve((size_t)N_NODES_PAD * D * 2);   // 51.2 MB
    int*      deg    = (int*)carve((size_t)N_NODES * 4);
    int*      offs   = (int*)carve((size_t)(N_NODES + 8) * 4);
    int*      cursor = (int*)carve((size_t)(N_NODES + 8) * 4);
    int*      bsum   = (int*)carve(1024);
    int2*     elist  = (int2*)carve((size_t)N_EDGES * 8);
    ushort_t* apack1 = (ushort_t*)carve((size_t)LAYERS * 32 * 8 * 64 * 8 * 2);   // 2 MB
    ushort_t* bpack2 = (ushort_t*)carve((size_t)LAYERS * 16 * 16 * 64 * 8 * 2);  // 2 MB

    const int NB = (N_NODES + SCAN_B - 1) / SCAN_B;   // 98

    // ---- one-time per call: weight pre-pack + CSR build ----
    pack1_k<<<256, 256, 0, stream>>>(W1, apack1);
    pack2_k<<<256, 256, 0, stream>>>(W2, bpack2);
    hipMemsetAsync(deg, 0, (size_t)N_NODES * 4, stream);
    count_k<<<(N_EDGES + 255) / 256, 256, 0, stream>>>(edge_index, deg);
    scan1_k<<<NB, 256, 0, stream>>>(deg, offs, bsum);
    scan2_k<<<1, 128, 0, stream>>>(bsum, NB);
    scan3_k<<<(N_NODES + 255) / 256, 256, 0, stream>>>(offs, cursor, bsum);
    fill_k<<<(N_EDGES + 255) / 256, 256, 0, stream>>>(edge_index, edge_attr, cursor, elist);

    encode_nodes_k<<<N_NODES, 256, 0, stream>>>(x_cat, node_emb, X);

    for (int l = 0; l < LAYERS; ++l) {
        gather_k<<<N_NODES / 4, 256, 0, stream>>>((const ushort4*)X, (const float4*)edge_emb,
                                                  offs, deg, elist, (ushort4*)H);
        mlp_k<<<(N_NODES_PAD) / BM, 512, 0, stream>>>(
            H,
            apack1 + (size_t)l * 32 * 8 * 64 * 8,
            b1 + (size_t)l * D2,
            bpack2 + (size_t)l * 16 * 16 * 64 * 8,
            b2 + (size_t)l * D,
            X);
    }

    final_k<<<N_GRAPHS / GB, 256, 0, stream>>>(X, batch, pW1, pb1, pW2, pb2, out);
}

// Round 6
// 713.496 us; speedup vs baseline: 12.4144x; 1.0528x over previous
//
#include <hip/hip_runtime.h>

#define N_NODES 100000
#define N_NODES_PAD 100032   // 1563 * 64
#define N_EDGES 200000
#define N_GRAPHS 4096
#define D 256
#define D2 512
#define OUTD 768
#define LAYERS 4
#define NODE_FEATS 9
#define EDGE_FEATS 3
#define NODE_VOCAB 119
#define EDGE_VOCAB 22
#define BM 64            // rows per MLP block
#define GB 8             // graphs per final block

typedef __attribute__((ext_vector_type(8))) short bf16x8;
typedef __attribute__((ext_vector_type(4))) float f32x4;
typedef unsigned short ushort_t;
typedef unsigned int uint_t;

__device__ __forceinline__ ushort_t f2b(float f) {   // f32 -> bf16 bits, RNE
    union { float f; uint_t u; } x; x.f = f;
    uint_t r = (x.u + 0x7FFFu + ((x.u >> 16) & 1u)) >> 16;
    return (ushort_t)r;
}
__device__ __forceinline__ float b2f(ushort_t u) {
    union { uint_t u; float f; } x; x.u = ((uint_t)u) << 16;
    return x.f;
}

__device__ __forceinline__ int lower_bound_i(const int* a, int n, int v) {
    int lo = 0, hi = n;
    while (lo < hi) { int mid = (lo + hi) >> 1; if (a[mid] < v) lo = mid + 1; else hi = mid; }
    return lo;
}

// ---------------- embedding encode (nodes), bf16 out ----------------
__global__ __launch_bounds__(256) void encode_nodes_k(const int* __restrict__ xcat,
                                                      const float* __restrict__ tab,
                                                      ushort_t* __restrict__ X) {
    int n = blockIdx.x, d = threadIdx.x;
    float acc = 0.f;
#pragma unroll
    for (int f = 0; f < NODE_FEATS; ++f) {
        int idx = xcat[n * NODE_FEATS + f];
        acc += tab[((size_t)f * NODE_VOCAB + idx) * D + d];
    }
    X[(size_t)n * D + d] = f2b(acc);
}

// ---------------- CSR build ----------------
__global__ __launch_bounds__(256) void count_k(const int* __restrict__ eidx, int* deg) {
    int e = blockIdx.x * 256 + threadIdx.x;
    if (e < N_EDGES) atomicAdd(&deg[eidx[N_EDGES + e]], 1);
}

#define SCAN_B 1024
__global__ __launch_bounds__(256) void scan1_k(const int* __restrict__ deg,
                                               int* __restrict__ excl, int* __restrict__ bsum) {
    __shared__ int sh[256];
    int b = blockIdx.x, t = threadIdx.x;
    int base = b * SCAN_B + t * 4;
    int d0 = (base + 0) < N_NODES ? deg[base + 0] : 0;
    int d1 = (base + 1) < N_NODES ? deg[base + 1] : 0;
    int d2 = (base + 2) < N_NODES ? deg[base + 2] : 0;
    int d3 = (base + 3) < N_NODES ? deg[base + 3] : 0;
    int s = d0 + d1 + d2 + d3;
    sh[t] = s; __syncthreads();
    for (int off = 1; off < 256; off <<= 1) {
        int x = (t >= off) ? sh[t - off] : 0;
        __syncthreads();
        sh[t] += x;
        __syncthreads();
    }
    int incl = sh[t];
    int ex = incl - s;
    if (base + 0 < N_NODES) excl[base + 0] = ex;
    if (base + 1 < N_NODES) excl[base + 1] = ex + d0;
    if (base + 2 < N_NODES) excl[base + 2] = ex + d0 + d1;
    if (base + 3 < N_NODES) excl[base + 3] = ex + d0 + d1 + d2;
    if (t == 255) bsum[b] = incl;
}

__global__ void scan2_k(int* bsum, int nb) {   // 1 block of 128 threads
    __shared__ int sh[128];
    int t = threadIdx.x;
    int v = (t < nb) ? bsum[t] : 0;
    sh[t] = v; __syncthreads();
    for (int off = 1; off < 128; off <<= 1) {
        int x = (t >= off) ? sh[t - off] : 0;
        __syncthreads();
        sh[t] += x;
        __syncthreads();
    }
    if (t < nb) bsum[t] = sh[t] - v;   // exclusive over blocks
}

__global__ __launch_bounds__(256) void scan3_k(int* __restrict__ offs, int* __restrict__ cursor,
                                               const int* __restrict__ bsum) {
    int i = blockIdx.x * 256 + threadIdx.x;
    if (i < N_NODES) {
        int v = offs[i] + bsum[i >> 10];
        offs[i] = v;
        cursor[i] = v;
    }
}

// elist entry: {src node, packed edge attrs}
__global__ __launch_bounds__(256) void fill_k(const int* __restrict__ eidx,
                                              const int* __restrict__ eattr,
                                              int* cursor, int2* __restrict__ elist) {
    int e = blockIdx.x * 256 + threadIdx.x;
    if (e < N_EDGES) {
        int src = eidx[e];
        int dst = eidx[N_EDGES + e];
        int pa = eattr[e * EDGE_FEATS + 0] | (eattr[e * EDGE_FEATS + 1] << 8)
               | (eattr[e * EDGE_FEATS + 2] << 16);
        int pos = atomicAdd(&cursor[dst], 1);
        elist[pos] = make_int2(src, pa);
    }
}

// -------- gather aggregation: H = bf16(X[n] + sum relu(X[src]+e_emb)) --------
// 4 nodes/block (1 wave each, deg wave-uniform); depth-1 prefetch of next edge.
__global__ __launch_bounds__(256) void gather_k(const ushort4* __restrict__ X4,
                                                const float4* __restrict__ eemb4,
                                                const int* __restrict__ offs,
                                                const int* __restrict__ deg,
                                                const int2* __restrict__ elist,
                                                ushort4* __restrict__ H4) {
    int n = blockIdx.x * 4 + (threadIdx.x >> 6);
    int lane = threadIdx.x & 63;
    int start = offs[n], dg = deg[n];
    ushort4 xv = X4[(size_t)n * 64 + lane];
    float acc[4] = {b2f(xv.x), b2f(xv.y), b2f(xv.z), b2f(xv.w)};
    if (dg > 0) {
        int2 sp = elist[start];
        ushort4 sv = X4[(size_t)sp.x * 64 + lane];
        for (int i = 0; i < dg; ++i) {
            int2 spn = sp; ushort4 svn = sv;
            if (i + 1 < dg) {
                spn = elist[start + i + 1];
                svn = X4[(size_t)spn.x * 64 + lane];
            }
            float4 t0 = eemb4[(size_t)((sp.y      ) & 255) * 64 + lane];
            float4 t1 = eemb4[((size_t)EDGE_VOCAB + ((sp.y >> 8) & 255)) * 64 + lane];
            float4 t2 = eemb4[((size_t)2 * EDGE_VOCAB + ((sp.y >> 16) & 255)) * 64 + lane];
            acc[0] += fmaxf(b2f(sv.x) + t0.x + t1.x + t2.x, 0.f);
            acc[1] += fmaxf(b2f(sv.y) + t0.y + t1.y + t2.y, 0.f);
            acc[2] += fmaxf(b2f(sv.z) + t0.z + t1.z + t2.z, 0.f);
            acc[3] += fmaxf(b2f(sv.w) + t0.w + t1.w + t2.w, 0.f);
            sp = spn; sv = svn;
        }
    }
    ushort4 hv;
    hv.x = f2b(acc[0]); hv.y = f2b(acc[1]); hv.z = f2b(acc[2]); hv.w = f2b(acc[3]);
    H4[(size_t)n * 64 + lane] = hv;
}

// ---------------- weight pre-pack into MFMA fragment layout (bf16) ----------------
__global__ __launch_bounds__(256) void pack1_k(const float* __restrict__ W1, ushort_t* __restrict__ apack) {
    size_t i = (size_t)blockIdx.x * 256 + threadIdx.x;   // 65536 groups
    int l = (int)(i >> 14);
    int rem = (int)(i & 16383);
    int ntg = rem >> 9;
    int rem2 = rem & 511;
    int kk = rem2 >> 6;
    int lane = rem2 & 63;
    int n = ntg * 16 + (lane & 15);
    int k0 = kk * 32 + (lane >> 4) * 8;
    const float* w = W1 + ((size_t)l * D + k0) * D2 + n;
    ushort_t* o = apack + i * 8;
#pragma unroll
    for (int j = 0; j < 8; ++j) o[j] = f2b(w[(size_t)j * D2]);
}

__global__ __launch_bounds__(256) void pack2_k(const float* __restrict__ W2, ushort_t* __restrict__ bpack) {
    size_t i = (size_t)blockIdx.x * 256 + threadIdx.x;   // 65536 groups
    int l = (int)(i >> 14);
    int rem = (int)(i & 16383);
    int ntg = rem >> 10;
    int rem2 = rem & 1023;
    int kk = rem2 >> 6;
    int lane = rem2 & 63;
    int n = ntg * 16 + (lane & 15);
    int k0 = kk * 32 + (lane >> 4) * 8;
    const float* w = W2 + ((size_t)l * D2 + k0) * D + n;
    ushort_t* o = bpack + i * 8;
#pragma unroll
    for (int j = 0; j < 8; ++j) o[j] = f2b(w[(size_t)j * D]);
}

// ---------------- fused MFMA MLP: X = relu(relu(H@W1+b1)@W2+b2) ----------------
// 512 threads = 8 waves, BM=64 rows, 64KB LDS -> 2 blocks/CU.
// Boundary weight fragments prefetched under pack/barrier; setprio around MFMA bursts.
__global__ __launch_bounds__(512, 4) void mlp_k(const ushort_t* __restrict__ H,
                                                const ushort_t* __restrict__ apack,
                                                const float* __restrict__ b1,
                                                const ushort_t* __restrict__ bpack,
                                                const float* __restrict__ b2,
                                                ushort_t* __restrict__ X) {
    __shared__ __align__(16) char hA[BM * 512];    // 32KB: 64 rows x 256 bf16, swizzled
    __shared__ __align__(16) char midh[BM * 512];  // 32KB: 64 rows x 256 bf16 (one n-half)
    const int t = threadIdx.x;
    const int wid = t >> 6, lane = t & 63;
    const int l15 = lane & 15, g = lane >> 4;
    const size_t r0 = (size_t)blockIdx.x * BM;

    // ---- stage H tile (64 rows, 32KB) with XOR swizzle ----
    {
        const char* src = (const char*)(H + r0 * D);
#pragma unroll
        for (int c = 0; c < 4; ++c) {
            int Lb = (c * 512 + t) * 16;
            int row = Lb >> 9;
            int Sb = Lb ^ ((row & 7) << 4);
            *(uint4*)(hA + Sb) = *(const uint4*)(src + Lb);
        }
    }

    f32x4 acc2[2][4];
#pragma unroll
    for (int a = 0; a < 2; ++a)
#pragma unroll
        for (int b = 0; b < 4; ++b) { f32x4 z = {0.f,0.f,0.f,0.f}; acc2[a][b] = z; }

    bf16x8 AfA[2], AfB[2], WfA[2], WfB[2];
    // prefetch GEMM1 half-0 first fragments (hides under the staging barrier)
#pragma unroll
    for (int nt = 0; nt < 2; ++nt)
        AfA[nt] = *(const bf16x8*)(apack + ((size_t)((0 * 16 + wid * 2 + nt) * 8 + 0) * 64 + lane) * 8);

    __syncthreads();

#pragma unroll
    for (int half = 0; half < 2; ++half) {
        // ---- GEMM1 (transposed): mid[:, half*256 + wid*32 ...] ----
        f32x4 acc1[2][4];
#pragma unroll
        for (int a = 0; a < 2; ++a)
#pragma unroll
            for (int b = 0; b < 4; ++b) { f32x4 z = {0.f,0.f,0.f,0.f}; acc1[a][b] = z; }

#pragma unroll
        for (int kk = 0; kk < 8; ++kk) {
            bf16x8 Bf[4];
#pragma unroll
            for (int mt = 0; mt < 4; ++mt) {
                int m = mt * 16 + l15;
                Bf[mt] = *(const bf16x8*)(hA + ((m * 512 + (kk * 32 + g * 8) * 2) ^ ((m & 7) << 4)));
            }
            bf16x8* cur = (kk & 1) ? AfB : AfA;   // kk is compile-time under unroll
            bf16x8* nxt = (kk & 1) ? AfA : AfB;
            if (kk < 7) {
#pragma unroll
                for (int nt = 0; nt < 2; ++nt)
                    nxt[nt] = *(const bf16x8*)(apack +
                        ((size_t)((half * 16 + wid * 2 + nt) * 8 + kk + 1) * 64 + lane) * 8);
            }
            __builtin_amdgcn_s_setprio(1);
#pragma unroll
            for (int nt = 0; nt < 2; ++nt)
#pragma unroll
                for (int mt = 0; mt < 4; ++mt)
                    acc1[nt][mt] = __builtin_amdgcn_mfma_f32_16x16x32_bf16(cur[nt], Bf[mt], acc1[nt][mt], 0, 0, 0);
            __builtin_amdgcn_s_setprio(0);
        }

        // prefetch GEMM2 first W2 fragments for this half (hides under pack + barrier)
#pragma unroll
        for (int nt = 0; nt < 2; ++nt)
            WfA[nt] = *(const bf16x8*)(bpack +
                ((size_t)((wid * 2 + nt) * 16 + half * 8 + 0) * 64 + lane) * 8);

        // bias + relu + pack to midh (lane holds 4 consecutive n at fixed m)
#pragma unroll
        for (int nt = 0; nt < 2; ++nt) {
            int n0l = (wid * 2 + nt) * 16 + g * 4;             // local col in half
            f32x4 bv = *(const f32x4*)(b1 + half * 256 + n0l);
#pragma unroll
            for (int mt = 0; mt < 4; ++mt) {
                int m = mt * 16 + l15;
                ushort_t us[4];
#pragma unroll
                for (int r = 0; r < 4; ++r)
                    us[r] = f2b(fmaxf(acc1[nt][mt][r] + bv[r], 0.f));
                uint2 pk;
                pk.x = (uint_t)us[0] | ((uint_t)us[1] << 16);
                pk.y = (uint_t)us[2] | ((uint_t)us[3] << 16);
                *(uint2*)(midh + ((m * 512 + n0l * 2) ^ ((m & 7) << 4))) = pk;
            }
        }
        __syncthreads();   // midh fully written

        // ---- GEMM2 partial (transposed): acc2 += mid_half @ W2[k-half] ----
#pragma unroll
        for (int kk = 0; kk < 8; ++kk) {
            bf16x8 Mf[4];
#pragma unroll
            for (int mt = 0; mt < 4; ++mt) {
                int m = mt * 16 + l15;
                Mf[mt] = *(const bf16x8*)(midh + ((m * 512 + (kk * 32 + g * 8) * 2) ^ ((m & 7) << 4)));
            }
            bf16x8* cur = (kk & 1) ? WfB : WfA;
            bf16x8* nxt = (kk & 1) ? WfA : WfB;
            if (kk < 7) {
#pragma unroll
                for (int nt = 0; nt < 2; ++nt)
                    nxt[nt] = *(const bf16x8*)(bpack +
                        ((size_t)((wid * 2 + nt) * 16 + half * 8 + kk + 1) * 64 + lane) * 8);
            }
            __builtin_amdgcn_s_setprio(1);
#pragma unroll
            for (int nt = 0; nt < 2; ++nt)
#pragma unroll
                for (int mt = 0; mt < 4; ++mt)
                    acc2[nt][mt] = __builtin_amdgcn_mfma_f32_16x16x32_bf16(cur[nt], Mf[mt], acc2[nt][mt], 0, 0, 0);
            __builtin_amdgcn_s_setprio(0);
        }

        // prefetch next half's GEMM1 first fragments (hides under tail barrier)
        if (half == 0) {
#pragma unroll
            for (int nt = 0; nt < 2; ++nt)
                AfA[nt] = *(const bf16x8*)(apack +
                    ((size_t)((1 * 16 + wid * 2 + nt) * 8 + 0) * 64 + lane) * 8);
        }
        __syncthreads();   // all reads of midh done before next half overwrites
    }

    // ---- epilogue GEMM2: lane holds 4 consecutive n at fixed m ----
#pragma unroll
    for (int nt = 0; nt < 2; ++nt) {
        int n0 = (wid * 2 + nt) * 16 + g * 4;
        f32x4 bv = *(const f32x4*)(b2 + n0);
#pragma unroll
        for (int mt = 0; mt < 4; ++mt) {
            int m = mt * 16 + l15;
            ushort_t us[4];
#pragma unroll
            for (int r = 0; r < 4; ++r)
                us[r] = f2b(fmaxf(acc2[nt][mt][r] + bv[r], 0.f));
            uint2 pk;
            pk.x = (uint_t)us[0] | ((uint_t)us[1] << 16);
            pk.y = (uint_t)us[2] | ((uint_t)us[3] << 16);
            *(uint2*)(X + (r0 + m) * D + n0) = pk;
        }
    }
}

// -------- fused pooling + final MLP + L2 normalize, GB=8 graphs per block --------
// pooling: 1 wave per graph (x2), ushort4 loads (8B/lane, one 512B row per iter).
__global__ __launch_bounds__(256) void final_k(const ushort4* __restrict__ X4,
                                               const int* __restrict__ batch,
                                               const float* __restrict__ pW1,
                                               const float* __restrict__ pb1,
                                               const float* __restrict__ pW2,
                                               const float* __restrict__ pb2,
                                               float* __restrict__ out) {
    __shared__ float gin[GB][D];    // 8KB
    __shared__ float mid[GB][D];    // 8KB
    __shared__ float red[GB][256];  // 8KB
    __shared__ int bnd[GB + 1];
    const int g0 = blockIdx.x * GB, t = threadIdx.x;
    const int wid = t >> 6, lane = t & 63;
    if (t <= GB) bnd[t] = lower_bound_i(batch, N_NODES, g0 + t);
    __syncthreads();

    // pooling: wave wid handles graphs wid and wid+4
#pragma unroll
    for (int qq = 0; qq < 2; ++qq) {
        int q = wid + qq * 4;
        f32x4 a = {0.f, 0.f, 0.f, 0.f};
        for (int n = bnd[q]; n < bnd[q + 1]; ++n) {
            ushort4 v = X4[(size_t)n * 64 + lane];
            a.x += b2f(v.x); a.y += b2f(v.y); a.z += b2f(v.z); a.w += b2f(v.w);
        }
        *(f32x4*)&gin[q][lane * 4] = a;
    }
    __syncthreads();

    // mlp1: mid = relu(gin @ pW1 + pb1)
    {
        float m_[GB];
        float bb = pb1[t];
#pragma unroll
        for (int q = 0; q < GB; ++q) m_[q] = bb;
        for (int k = 0; k < D; ++k) {
            float w = pW1[(size_t)k * D + t];
#pragma unroll
            for (int q = 0; q < GB; ++q) m_[q] += gin[q][k] * w;
        }
#pragma unroll
        for (int q = 0; q < GB; ++q) mid[q][t] = fmaxf(m_[q], 0.f);
    }
    __syncthreads();

    // mlp2 + norm
    float a0[GB], a1[GB], a2[GB];
    {
        float b0 = pb2[t], b1_ = pb2[t + 256], b2_ = pb2[t + 512];
#pragma unroll
        for (int q = 0; q < GB; ++q) { a0[q] = b0; a1[q] = b1_; a2[q] = b2_; }
        for (int k = 0; k < D; ++k) {
            float w0 = pW2[(size_t)k * OUTD + t];
            float w1 = pW2[(size_t)k * OUTD + 256 + t];
            float w2 = pW2[(size_t)k * OUTD + 512 + t];
#pragma unroll
            for (int q = 0; q < GB; ++q) {
                float mv = mid[q][k];
                a0[q] += mv * w0; a1[q] += mv * w1; a2[q] += mv * w2;
            }
        }
    }
#pragma unroll
    for (int q = 0; q < GB; ++q)
        red[q][t] = a0[q] * a0[q] + a1[q] * a1[q] + a2[q] * a2[q];
    __syncthreads();
    for (int s = 128; s > 0; s >>= 1) {
        if (t < s) {
#pragma unroll
            for (int q = 0; q < GB; ++q) red[q][t] += red[q][t + s];
        }
        __syncthreads();
    }
#pragma unroll
    for (int q = 0; q < GB; ++q) {
        float inv = 1.f / fmaxf(sqrtf(red[q][0]), 1e-12f);
        out[(size_t)(g0 + q) * OUTD + t]       = a0[q] * inv;
        out[(size_t)(g0 + q) * OUTD + 256 + t] = a1[q] * inv;
        out[(size_t)(g0 + q) * OUTD + 512 + t] = a2[q] * inv;
    }
}

extern "C" void kernel_launch(void* const* d_in, const int* in_sizes, int n_in,
                              void* d_out, int out_size, void* d_ws, size_t ws_size,
                              hipStream_t stream) {
    const int*   x_cat      = (const int*)d_in[0];
    const int*   edge_attr  = (const int*)d_in[1];
    const int*   edge_index = (const int*)d_in[2];
    const int*   batch      = (const int*)d_in[3];
    const float* node_emb   = (const float*)d_in[4];
    const float* edge_emb   = (const float*)d_in[5];
    const float* W1  = (const float*)d_in[6];
    const float* b1  = (const float*)d_in[7];
    const float* W2  = (const float*)d_in[8];
    const float* b2  = (const float*)d_in[9];
    const float* pW1 = (const float*)d_in[10];
    const float* pb1 = (const float*)d_in[11];
    const float* pW2 = (const float*)d_in[12];
    const float* pb2 = (const float*)d_in[13];
    float* out = (float*)d_out;

    // ---- workspace carve (~112 MB) ----
    char* p = (char*)d_ws;
    auto carve = [&](size_t bytes) { char* q = p; p += (bytes + 255) & ~(size_t)255; return q; };
    ushort_t* X      = (ushort_t*)carve((size_t)N_NODES_PAD * D * 2);   // 51.2 MB
    ushort_t* H      = (ushort_t*)carve((size_t)N_NODES_PAD * D * 2);   // 51.2 MB
    int*      deg    = (int*)carve((size_t)N_NODES * 4);
    int*      offs   = (int*)carve((size_t)(N_NODES + 8) * 4);
    int*      cursor = (int*)carve((size_t)(N_NODES + 8) * 4);
    int*      bsum   = (int*)carve(1024);
    int2*     elist  = (int2*)carve((size_t)N_EDGES * 8);
    ushort_t* apack1 = (ushort_t*)carve((size_t)LAYERS * 32 * 8 * 64 * 8 * 2);   // 2 MB
    ushort_t* bpack2 = (ushort_t*)carve((size_t)LAYERS * 16 * 16 * 64 * 8 * 2);  // 2 MB

    const int NB = (N_NODES + SCAN_B - 1) / SCAN_B;   // 98

    // ---- one-time per call: weight pre-pack + CSR build ----
    pack1_k<<<256, 256, 0, stream>>>(W1, apack1);
    pack2_k<<<256, 256, 0, stream>>>(W2, bpack2);
    hipMemsetAsync(deg, 0, (size_t)N_NODES * 4, stream);
    count_k<<<(N_EDGES + 255) / 256, 256, 0, stream>>>(edge_index, deg);
    scan1_k<<<NB, 256, 0, stream>>>(deg, offs, bsum);
    scan2_k<<<1, 128, 0, stream>>>(bsum, NB);
    scan3_k<<<(N_NODES + 255) / 256, 256, 0, stream>>>(offs, cursor, bsum);
    fill_k<<<(N_EDGES + 255) / 256, 256, 0, stream>>>(edge_index, edge_attr, cursor, elist);

    encode_nodes_k<<<N_NODES, 256, 0, stream>>>(x_cat, node_emb, X);

    for (int l = 0; l < LAYERS; ++l) {
        gather_k<<<N_NODES / 4, 256, 0, stream>>>((const ushort4*)X, (const float4*)edge_emb,
                                                  offs, deg, elist, (ushort4*)H);
        mlp_k<<<(N_NODES_PAD) / BM, 512, 0, stream>>>(
            H,
            apack1 + (size_t)l * 32 * 8 * 64 * 8,
            b1 + (size_t)l * D2,
            bpack2 + (size_t)l * 16 * 16 * 64 * 8,
            b2 + (size_t)l * D,
            X);
    }

    final_k<<<N_GRAPHS / GB, 256, 0, stream>>>((const ushort4*)X, batch, pW1, pb1, pW2, pb2, out);
}